// Round 1
// baseline (1773.436 us; speedup 1.0000x reference)
//
#include <hip/hip_runtime.h>
#include <math.h>

#define LATN 512
#define FINN 256
#define FOUTN 256
#define NB 16
#define HH 64
#define WW 64

// ---------------- style MLP layer: out[b][j] = act(sum_k in[b][k]*w[j][k]*scale + bias[j]) ----
// 16 lanes per output j; block = 256 threads -> 16 j per block. grid = (out_dim/16, B)
__global__ void style_layer_kernel(const float* __restrict__ in,
                                   const float* __restrict__ w,
                                   const float* __restrict__ bias,
                                   float* __restrict__ out,
                                   int in_dim, int out_dim,
                                   float scale, int do_lrelu) {
    int t = threadIdx.x;
    int jl = t >> 4;
    int kl = t & 15;
    int j = blockIdx.x * 16 + jl;
    int b = blockIdx.y;
    const float* inr = in + (size_t)b * in_dim;
    const float* wr  = w + (size_t)j * in_dim;
    float sum = 0.f;
    for (int k = kl; k < in_dim; k += 16)
        sum += inr[k] * wr[k];
    #pragma unroll
    for (int off = 8; off >= 1; off >>= 1)
        sum += __shfl_xor(sum, off, 16);
    if (kl == 0) {
        float v = sum * scale + bias[j];
        if (do_lrelu && v < 0.f) v *= 0.2f;
        out[(size_t)b * out_dim + j] = v;
    }
}

// ---------------- normalize styles by per-sample inf-norm (in place). grid=B, block=256 ------
__global__ void norm_styles_kernel(float* __restrict__ s) {
    __shared__ float red[256];
    int b = blockIdx.x, t = threadIdx.x;
    float v = s[(size_t)b * FINN + t];
    red[t] = fabsf(v);
    __syncthreads();
    for (int k = 128; k > 0; k >>= 1) {
        if (t < k) red[t] = fmaxf(red[t], red[t + k]);
        __syncthreads();
    }
    float m = red[0];
    s[(size_t)b * FINN + t] = v / m;
}

// ---------------- weight prep: mw = weight * (1/48 / maxabs_per_o); mw2sum[o][i]=sum taps mw^2
// grid = FOUT (one block per o), block = 256 (one thread per i)
__global__ void weight_prep_kernel(const float* __restrict__ weight,
                                   float* __restrict__ mw,
                                   float* __restrict__ mw2sum) {
    __shared__ float red[256];
    int o = blockIdx.x, t = threadIdx.x;
    const float* wrow = weight + ((size_t)o * FINN + t) * 9;
    float wv[9];
    float mx = 0.f;
    #pragma unroll
    for (int k = 0; k < 9; ++k) { wv[k] = wrow[k]; mx = fmaxf(mx, fabsf(wv[k])); }
    red[t] = mx;
    __syncthreads();
    for (int k = 128; k > 0; k >>= 1) {
        if (t < k) red[t] = fmaxf(red[t], red[t + k]);
        __syncthreads();
    }
    float scale = (1.0f / 48.0f) / red[0];   // 1/sqrt(256*9) = 1/48
    float* mrow = mw + ((size_t)o * FINN + t) * 9;
    float s2 = 0.f;
    #pragma unroll
    for (int k = 0; k < 9; ++k) { float m = wv[k] * scale; mrow[k] = m; s2 += m * m; }
    mw2sum[(size_t)o * FINN + t] = s2;
}

// ---------------- dcoefs[b][o] = rsqrt(sum_i mw2sum[o][i]*s[b][i]^2 + 1e-8). grid=B, block=FOUT
__global__ void dcoef_kernel(const float* __restrict__ mw2sum,
                             const float* __restrict__ s,
                             float* __restrict__ dcoefs) {
    int b = blockIdx.x, o = threadIdx.x;
    const float* srow = s + (size_t)b * FINN;
    const float* m2 = mw2sum + (size_t)o * FINN;
    float sum = 0.f;
    for (int i = 0; i < FINN; ++i) {
        float si = srow[i];
        sum += m2[i] * si * si;
    }
    dcoefs[(size_t)b * FOUTN + o] = rsqrtf(sum + 1e-8f);
}

// ---------------- main conv: y[b,o,h,w] = dco[b,o] * sum_{i,kh,kw} mw[o,i,kh,kw]*s[b,i]*x[b,i,h+kh-1,w+kw-1]
// Tile: 64 output channels x 8x8 spatial per block (256 threads, 4o x 4sp per thread).
// grid = (64 spatial tiles, FOUT/64, B)
#define OT  64
#define ICC 8
__global__ __launch_bounds__(256) void conv_kernel(
    const float* __restrict__ x, const float* __restrict__ snorm,
    const float* __restrict__ mw, const float* __restrict__ dcoefs,
    float* __restrict__ y) {
    __shared__ float xs[ICC * 10 * 12];      // [c][row 0..9][col 0..9 pad 12]
    __shared__ float wl[ICC * 9 * OT];       // [(c*9+tap)*64 + o_local]
    int t = threadIdx.x;
    int tile = blockIdx.x;                   // 0..63
    int ob = blockIdx.y * OT;
    int b = blockIdx.z;
    int h0 = (tile >> 3) << 3;
    int w0 = (tile & 7) << 3;

    int to  = t >> 4;        // 0..15 -> o group of 4
    int ts  = t & 15;        // 0..15 -> spatial group of 4
    int sh  = ts >> 1;       // row 0..7
    int swb = (ts & 1) << 2; // col base 0 or 4

    float acc[4][4];
    #pragma unroll
    for (int j = 0; j < 4; ++j)
        #pragma unroll
        for (int m = 0; m < 4; ++m) acc[j][m] = 0.f;

    const float* xb = x + (size_t)b * FINN * HH * WW;
    const float* sn = snorm + (size_t)b * FINN;

    for (int ic0 = 0; ic0 < FINN; ic0 += ICC) {
        if (ic0) __syncthreads();
        // load x tile (with style modulation folded in), zero-padded borders
        for (int e = t; e < ICC * 100; e += 256) {
            int c  = e / 100;
            int r  = (e % 100) / 10;
            int cc = e % 10;
            int gh = h0 - 1 + r;
            int gw = w0 - 1 + cc;
            float v = 0.f;
            if (gh >= 0 && gh < HH && gw >= 0 && gw < WW)
                v = xb[((size_t)(ic0 + c) * HH + gh) * WW + gw] * sn[ic0 + c];
            xs[c * 120 + r * 12 + cc] = v;
        }
        // load weights for this (o-block, ic chunk)
        for (int e = t; e < ICC * 9 * OT; e += 256) {
            int o_l = e / 72;
            int rem = e % 72;
            int c   = rem / 9;
            int tap = rem % 9;
            wl[(c * 9 + tap) * OT + o_l] =
                mw[((size_t)(ob + o_l) * FINN + ic0 + c) * 9 + tap];
        }
        __syncthreads();
        // compute
        #pragma unroll
        for (int c = 0; c < ICC; ++c) {
            #pragma unroll
            for (int kh = 0; kh < 3; ++kh) {
                float xr[6];
                #pragma unroll
                for (int n = 0; n < 6; ++n)
                    xr[n] = xs[c * 120 + (sh + kh) * 12 + swb + n];
                #pragma unroll
                for (int kw = 0; kw < 3; ++kw) {
                    float wv[4];
                    #pragma unroll
                    for (int j = 0; j < 4; ++j)
                        wv[j] = wl[(c * 9 + kh * 3 + kw) * OT + to * 4 + j];
                    #pragma unroll
                    for (int j = 0; j < 4; ++j)
                        #pragma unroll
                        for (int m = 0; m < 4; ++m)
                            acc[j][m] += wv[j] * xr[kw + m];
                }
            }
        }
    }
    // epilogue: demodulation scale + store
    #pragma unroll
    for (int j = 0; j < 4; ++j) {
        int o = ob + to * 4 + j;
        float d = dcoefs[(size_t)b * FOUTN + o];
        #pragma unroll
        for (int m = 0; m < 4; ++m)
            y[(((size_t)b * FOUTN + o) * HH + h0 + sh) * WW + w0 + swb + m] =
                acc[j][m] * d;
    }
}

extern "C" void kernel_launch(void* const* d_in, const int* in_sizes, int n_in,
                              void* d_out, int out_size, void* d_ws, size_t ws_size,
                              hipStream_t stream) {
    const float* x      = (const float*)d_in[0];
    const float* lat    = (const float*)d_in[1];
    const float* weight = (const float*)d_in[2];
    const float* ws     = (const float*)d_in[3];
    const float* bs     = (const float*)d_in[4];
    const float* wf     = (const float*)d_in[5];
    const float* bf     = (const float*)d_in[6];
    float* y = (float*)d_out;

    float* W    = (float*)d_ws;
    float* hA   = W;                      // 16*512
    float* hB   = W + 8192;               // 16*512
    float* sty  = W + 16384;              // 16*256
    float* mw   = W + 20480;              // 256*256*9
    float* mw2  = W + 20480 + 589824;     // 256*256
    float* dco  = W + 20480 + 589824 + 65536; // 16*256

    float eq = 1.0f / sqrtf((float)LATN);

    // style MLP: 4 EqualLinear+LeakyReLU layers
    style_layer_kernel<<<dim3(LATN / 16, NB), 256, 0, stream>>>(
        lat, ws + 0 * LATN * LATN, bs + 0 * LATN, hA, LATN, LATN, eq, 1);
    style_layer_kernel<<<dim3(LATN / 16, NB), 256, 0, stream>>>(
        hA, ws + 1 * (size_t)LATN * LATN, bs + 1 * LATN, hB, LATN, LATN, eq, 1);
    style_layer_kernel<<<dim3(LATN / 16, NB), 256, 0, stream>>>(
        hB, ws + 2 * (size_t)LATN * LATN, bs + 2 * LATN, hA, LATN, LATN, eq, 1);
    style_layer_kernel<<<dim3(LATN / 16, NB), 256, 0, stream>>>(
        hA, ws + 3 * (size_t)LATN * LATN, bs + 3 * LATN, hB, LATN, LATN, eq, 1);
    // final plain linear -> styles [B, FIN]
    style_layer_kernel<<<dim3(FINN / 16, NB), 256, 0, stream>>>(
        hB, wf, bf, sty, LATN, FINN, 1.0f, 0);
    // normalize styles by per-sample inf-norm
    norm_styles_kernel<<<NB, 256, 0, stream>>>(sty);
    // weight normalization + per-(o,i) sum of squares
    weight_prep_kernel<<<FOUTN, 256, 0, stream>>>(weight, mw, mw2);
    // demod coefficients
    dcoef_kernel<<<NB, FOUTN, 0, stream>>>(mw2, sty, dco);
    // main conv
    conv_kernel<<<dim3(64, FOUTN / OT, NB), 256, 0, stream>>>(x, sty, mw, dco, y);
}

// Round 2
// 146.057 us; speedup vs baseline: 12.1421x; 12.1421x over previous
//
#include <hip/hip_runtime.h>
#include <hip/hip_bf16.h>
#include <math.h>

#define LATN 512
#define FINN 256
#define FOUTN 256
#define NB 16
#define HH 64
#define WW 64

typedef __attribute__((ext_vector_type(8))) short bf16x8;
typedef __attribute__((ext_vector_type(4))) float f32x4;

// ---------------- style MLP layer ----------------
__global__ void style_layer_kernel(const float* __restrict__ in,
                                   const float* __restrict__ w,
                                   const float* __restrict__ bias,
                                   float* __restrict__ out,
                                   int in_dim, int out_dim,
                                   float scale, int do_lrelu) {
    int t = threadIdx.x;
    int jl = t >> 4;
    int kl = t & 15;
    int j = blockIdx.x * 16 + jl;
    int b = blockIdx.y;
    const float* inr = in + (size_t)b * in_dim;
    const float* wr  = w + (size_t)j * in_dim;
    float sum = 0.f;
    for (int k = kl; k < in_dim; k += 16)
        sum += inr[k] * wr[k];
    #pragma unroll
    for (int off = 8; off >= 1; off >>= 1)
        sum += __shfl_xor(sum, off, 16);
    if (kl == 0) {
        float v = sum * scale + bias[j];
        if (do_lrelu && v < 0.f) v *= 0.2f;
        out[(size_t)b * out_dim + j] = v;
    }
}

// ---------------- normalize styles ----------------
__global__ void norm_styles_kernel(float* __restrict__ s) {
    __shared__ float red[256];
    int b = blockIdx.x, t = threadIdx.x;
    float v = s[(size_t)b * FINN + t];
    red[t] = fabsf(v);
    __syncthreads();
    for (int k = 128; k > 0; k >>= 1) {
        if (t < k) red[t] = fmaxf(red[t], red[t + k]);
        __syncthreads();
    }
    float m = red[0];
    s[(size_t)b * FINN + t] = v / m;
}

// ---------------- OLD fp32 weight prep (fallback) ----------------
__global__ void weight_prep_kernel(const float* __restrict__ weight,
                                   float* __restrict__ mw,
                                   float* __restrict__ mw2sum) {
    __shared__ float red[256];
    int o = blockIdx.x, t = threadIdx.x;
    const float* wrow = weight + ((size_t)o * FINN + t) * 9;
    float wv[9];
    float mx = 0.f;
    #pragma unroll
    for (int k = 0; k < 9; ++k) { wv[k] = wrow[k]; mx = fmaxf(mx, fabsf(wv[k])); }
    red[t] = mx;
    __syncthreads();
    for (int k = 128; k > 0; k >>= 1) {
        if (t < k) red[t] = fmaxf(red[t], red[t + k]);
        __syncthreads();
    }
    float scale = (1.0f / 48.0f) / red[0];
    float* mrow = mw + ((size_t)o * FINN + t) * 9;
    float s2 = 0.f;
    #pragma unroll
    for (int k = 0; k < 9; ++k) { float m = wv[k] * scale; mrow[k] = m; s2 += m * m; }
    mw2sum[(size_t)o * FINN + t] = s2;
}

// ---------------- NEW weight prep: wfmt bf16 staged-image layout + mw2sum ----------------
// wfmt[ob][ch][tap][ol(64)][il(32)], ob=o>>6, ch=i>>5
__global__ void weight_prep_new_kernel(const float* __restrict__ weight,
                                       __hip_bfloat16* __restrict__ wfmt,
                                       float* __restrict__ mw2sum) {
    __shared__ float red[256];
    int o = blockIdx.x, t = threadIdx.x;
    const float* wrow = weight + ((size_t)o * FINN + t) * 9;
    float wv[9];
    float mx = 0.f;
    #pragma unroll
    for (int k = 0; k < 9; ++k) { wv[k] = wrow[k]; mx = fmaxf(mx, fabsf(wv[k])); }
    red[t] = mx;
    __syncthreads();
    for (int k = 128; k > 0; k >>= 1) {
        if (t < k) red[t] = fmaxf(red[t], red[t + k]);
        __syncthreads();
    }
    float scale = (1.0f / 48.0f) / red[0];
    int ob = o >> 6, ol = o & 63, ch = t >> 5, il = t & 31;
    float s2 = 0.f;
    #pragma unroll
    for (int tap = 0; tap < 9; ++tap) {
        float m = wv[tap] * scale;
        s2 += m * m;
        wfmt[((((size_t)ob * 8 + ch) * 9 + tap) * 64 + ol) * 32 + il] = __float2bfloat16(m);
    }
    mw2sum[(size_t)o * FINN + t] = s2;
}

// ---------------- dcoefs ----------------
__global__ void dcoef_kernel(const float* __restrict__ mw2sum,
                             const float* __restrict__ s,
                             float* __restrict__ dcoefs) {
    int b = blockIdx.x, o = threadIdx.x;
    const float* srow = s + (size_t)b * FINN;
    const float* m2 = mw2sum + (size_t)o * FINN;
    float sum = 0.f;
    for (int i = 0; i < FINN; ++i) {
        float si = srow[i];
        sum += m2[i] * si * si;
    }
    dcoefs[(size_t)b * FOUTN + o] = rsqrtf(sum + 1e-8f);
}

// ---------------- zero pad buffer ----------------
__global__ void init_zero_kernel(float* __restrict__ z) {
    z[threadIdx.x] = 0.f;
}

// ---------------- x NCHW fp32 -> xm NHWC bf16 (style folded) ----------------
__global__ __launch_bounds__(256) void xcvt_kernel(const float* __restrict__ x,
                                                   const float* __restrict__ sn,
                                                   __hip_bfloat16* __restrict__ xm) {
    __shared__ float tile[64][65];
    int h = blockIdx.x, b = blockIdx.y;
    int t = threadIdx.x;
    int wl_ = t & 63;
    int ig = t >> 6;
    for (int icb = 0; icb < 4; ++icb) {
        if (icb) __syncthreads();
        #pragma unroll
        for (int p = 0; p < 16; ++p) {
            int i_l = p * 4 + ig;
            int i = icb * 64 + i_l;
            tile[i_l][wl_] = x[(((size_t)b * FINN + i) * HH + h) * WW + wl_]
                             * sn[(size_t)b * FINN + i];
        }
        __syncthreads();
        #pragma unroll
        for (int p = 0; p < 8; ++p) {
            int u = p * 256 + t;
            int w = u >> 5;
            int pr = u & 31;
            __hip_bfloat162 v;
            v.x = __float2bfloat16(tile[pr * 2][w]);
            v.y = __float2bfloat16(tile[pr * 2 + 1][w]);
            *(__hip_bfloat162*)(&xm[(((size_t)b * 4096 + h * 64 + w) * 256) + icb * 64 + pr * 2]) = v;
        }
    }
}

// ---------------- global_load_lds helper ----------------
__device__ __forceinline__ void gl_lds16(const void* g, void* l) {
    __builtin_amdgcn_global_load_lds(
        (const __attribute__((address_space(1))) unsigned int*)g,
        (__attribute__((address_space(3))) unsigned int*)l, 16, 0, 0);
}

// ---------------- MFMA conv ----------------
// grid (16 sp, 4 ob, 16 b), 256 threads (4 waves). Block tile: O=64, 4 rows x 64 w.
// Wave wid owns row h0+wid; computes O=64 x W=64 via 4x4 tiles of 16x16, K=32/chunk.
__global__ __launch_bounds__(256) void mconv_kernel(
    const __hip_bfloat16* __restrict__ xm,
    const __hip_bfloat16* __restrict__ wfmt,
    const float* __restrict__ dco,
    const float* __restrict__ zerobuf,
    float* __restrict__ y) {
    __shared__ __hip_bfloat16 xs[14336];   // 6*66*32 real (25344B) + slack = 28672B
    __shared__ __hip_bfloat16 wl[18432];   // [9][64][32] = 36864B

    int t = threadIdx.x;
    int lane = t & 63;
    int wid = t >> 6;
    int h0 = blockIdx.x * 4;
    int obi = blockIdx.y;
    int ob = obi * 64;
    int b = blockIdx.z;

    // precompute x-staging source pointers (7 issues/wave)
    const char* srcq[7];
    int incq[7];
    const __hip_bfloat16* xb = xm + (size_t)b * 4096 * 256;
    #pragma unroll
    for (int q = 0; q < 7; ++q) {
        int u = (wid * 7 + q) * 64 + lane;
        int p = u >> 2, iq = u & 3;
        int r = p / 66, c = p % 66;
        int gh = h0 - 1 + r, gw = c - 1;
        bool v = (u < 1584) && (gh >= 0) && (gh < HH) && (gw >= 0) && (gw < WW);
        srcq[q] = v ? (const char*)(xb + ((size_t)(gh * 64 + gw)) * 256 + iq * 8)
                    : (const char*)zerobuf;
        incq[q] = v ? 64 : 0;   // 32 bf16 elems per K-chunk
    }
    const __hip_bfloat16* wsrc = wfmt + (size_t)obi * 8 * 18432 + (wid * 9) * 512 + lane * 8;

    f32x4 acc[4][4] = {};
    int l15 = lane & 15, lg = lane >> 4;
    int frag_off = l15 * 64 + lg * 16;   // bytes
    const char* xs_b = (const char*)xs;
    const char* wl_b = (const char*)wl;

    for (int ch = 0; ch < 8; ++ch) {
        if (ch) __syncthreads();
        // stage x tile
        #pragma unroll
        for (int q = 0; q < 7; ++q) {
            gl_lds16(srcq[q], (char*)xs + (wid * 7 + q) * 1024);
            srcq[q] += incq[q];
        }
        // stage weights (linear copy)
        #pragma unroll
        for (int q = 0; q < 9; ++q)
            gl_lds16(wsrc + q * 512, (char*)wl + (wid * 9 + q) * 1024);
        wsrc += 18432;
        __syncthreads();
        // compute 9 taps
        #pragma unroll
        for (int kh = 0; kh < 3; ++kh) {
            #pragma unroll
            for (int kw = 0; kw < 3; ++kw) {
                int tap = kh * 3 + kw;
                bf16x8 af[4], bfr[4];
                #pragma unroll
                for (int mt = 0; mt < 4; ++mt)
                    af[mt] = *(const bf16x8*)(wl_b + tap * 4096 + mt * 1024 + frag_off);
                int xrow = ((wid + kh) * 66 + kw) * 64;
                #pragma unroll
                for (int nt = 0; nt < 4; ++nt)
                    bfr[nt] = *(const bf16x8*)(xs_b + xrow + nt * 1024 + frag_off);
                #pragma unroll
                for (int mt = 0; mt < 4; ++mt)
                    #pragma unroll
                    for (int nt = 0; nt < 4; ++nt)
                        acc[mt][nt] = __builtin_amdgcn_mfma_f32_16x16x32_bf16(
                            af[mt], bfr[nt], acc[mt][nt], 0, 0, 0);
            }
        }
    }

    // epilogue: demod + store
    const float* dcb = dco + (size_t)b * FOUTN + ob;
    float* yb = y + (((size_t)b * FOUTN + ob) * HH + (h0 + wid)) * WW;
    #pragma unroll
    for (int mt = 0; mt < 4; ++mt) {
        #pragma unroll
        for (int j = 0; j < 4; ++j) {
            int o_l = mt * 16 + lg * 4 + j;
            float d = dcb[o_l];
            #pragma unroll
            for (int nt = 0; nt < 4; ++nt)
                yb[(size_t)o_l * 4096 + nt * 16 + l15] = acc[mt][nt][j] * d;
        }
    }
}

// ---------------- OLD fp32 conv (fallback) ----------------
#define OT  64
#define ICCF 8
__global__ __launch_bounds__(256) void conv_kernel(
    const float* __restrict__ x, const float* __restrict__ snorm,
    const float* __restrict__ mw, const float* __restrict__ dcoefs,
    float* __restrict__ y) {
    __shared__ float xsf[ICCF * 10 * 12];
    __shared__ float wlf[ICCF * 9 * OT];
    int t = threadIdx.x;
    int tile = blockIdx.x;
    int ob = blockIdx.y * OT;
    int b = blockIdx.z;
    int h0 = (tile >> 3) << 3;
    int w0 = (tile & 7) << 3;
    int to  = t >> 4;
    int ts  = t & 15;
    int sh  = ts >> 1;
    int swb = (ts & 1) << 2;
    float acc[4][4];
    #pragma unroll
    for (int j = 0; j < 4; ++j)
        #pragma unroll
        for (int m = 0; m < 4; ++m) acc[j][m] = 0.f;
    const float* xb = x + (size_t)b * FINN * HH * WW;
    const float* sn = snorm + (size_t)b * FINN;
    for (int ic0 = 0; ic0 < FINN; ic0 += ICCF) {
        if (ic0) __syncthreads();
        for (int e = t; e < ICCF * 100; e += 256) {
            int c  = e / 100;
            int r  = (e % 100) / 10;
            int cc = e % 10;
            int gh = h0 - 1 + r;
            int gw = w0 - 1 + cc;
            float v = 0.f;
            if (gh >= 0 && gh < HH && gw >= 0 && gw < WW)
                v = xb[((size_t)(ic0 + c) * HH + gh) * WW + gw] * sn[ic0 + c];
            xsf[c * 120 + r * 12 + cc] = v;
        }
        for (int e = t; e < ICCF * 9 * OT; e += 256) {
            int o_l = e / 72;
            int rem = e % 72;
            int c   = rem / 9;
            int tap = rem % 9;
            wlf[(c * 9 + tap) * OT + o_l] =
                mw[((size_t)(ob + o_l) * FINN + ic0 + c) * 9 + tap];
        }
        __syncthreads();
        #pragma unroll
        for (int c = 0; c < ICCF; ++c) {
            #pragma unroll
            for (int kh = 0; kh < 3; ++kh) {
                float xr[6];
                #pragma unroll
                for (int n = 0; n < 6; ++n)
                    xr[n] = xsf[c * 120 + (sh + kh) * 12 + swb + n];
                #pragma unroll
                for (int kw = 0; kw < 3; ++kw) {
                    float wv[4];
                    #pragma unroll
                    for (int j = 0; j < 4; ++j)
                        wv[j] = wlf[(c * 9 + kh * 3 + kw) * OT + to * 4 + j];
                    #pragma unroll
                    for (int j = 0; j < 4; ++j)
                        #pragma unroll
                        for (int m = 0; m < 4; ++m)
                            acc[j][m] += wv[j] * xr[kw + m];
                }
            }
        }
    }
    #pragma unroll
    for (int j = 0; j < 4; ++j) {
        int o = ob + to * 4 + j;
        float d = dcoefs[(size_t)b * FOUTN + o];
        #pragma unroll
        for (int m = 0; m < 4; ++m)
            y[(((size_t)b * FOUTN + o) * HH + h0 + sh) * WW + w0 + swb + m] =
                acc[j][m] * d;
    }
}

extern "C" void kernel_launch(void* const* d_in, const int* in_sizes, int n_in,
                              void* d_out, int out_size, void* d_ws, size_t ws_size,
                              hipStream_t stream) {
    const float* x      = (const float*)d_in[0];
    const float* lat    = (const float*)d_in[1];
    const float* weight = (const float*)d_in[2];
    const float* ws     = (const float*)d_in[3];
    const float* bs     = (const float*)d_in[4];
    const float* wf     = (const float*)d_in[5];
    const float* bf     = (const float*)d_in[6];
    float* y = (float*)d_out;

    float* W    = (float*)d_ws;
    float* hA   = W;                 // 8192 f
    float* hB   = W + 8192;          // 8192 f
    float* sty  = W + 16384;         // 4096 f
    float* mw2  = W + 20480;         // 65536 f
    float* dco  = W + 86016;         // 4096 f
    float* zero = W + 90112;         // 64 f
    // new path (bytes): wfmt @360704, xm @1540352
    __hip_bfloat16* wfmt = (__hip_bfloat16*)((char*)d_ws + 360704);
    __hip_bfloat16* xm   = (__hip_bfloat16*)((char*)d_ws + 1540352);
    // old path
    float* mw = W + 90176;           // 589824 f

    const size_t NEED_NEW = 1540352 + 33554432;
    bool fast = ws_size >= NEED_NEW;

    float eq = 1.0f / sqrtf((float)LATN);

    style_layer_kernel<<<dim3(LATN / 16, NB), 256, 0, stream>>>(
        lat, ws + 0 * (size_t)LATN * LATN, bs + 0 * LATN, hA, LATN, LATN, eq, 1);
    style_layer_kernel<<<dim3(LATN / 16, NB), 256, 0, stream>>>(
        hA, ws + 1 * (size_t)LATN * LATN, bs + 1 * LATN, hB, LATN, LATN, eq, 1);
    style_layer_kernel<<<dim3(LATN / 16, NB), 256, 0, stream>>>(
        hB, ws + 2 * (size_t)LATN * LATN, bs + 2 * LATN, hA, LATN, LATN, eq, 1);
    style_layer_kernel<<<dim3(LATN / 16, NB), 256, 0, stream>>>(
        hA, ws + 3 * (size_t)LATN * LATN, bs + 3 * LATN, hB, LATN, LATN, eq, 1);
    style_layer_kernel<<<dim3(FINN / 16, NB), 256, 0, stream>>>(
        hB, wf, bf, sty, LATN, FINN, 1.0f, 0);
    norm_styles_kernel<<<NB, 256, 0, stream>>>(sty);

    if (fast) {
        weight_prep_new_kernel<<<FOUTN, 256, 0, stream>>>(weight, wfmt, mw2);
        dcoef_kernel<<<NB, FOUTN, 0, stream>>>(mw2, sty, dco);
        init_zero_kernel<<<1, 64, 0, stream>>>(zero);
        xcvt_kernel<<<dim3(HH, NB), 256, 0, stream>>>(x, sty, xm);
        mconv_kernel<<<dim3(16, 4, NB), 256, 0, stream>>>(xm, wfmt, dco, zero, y);
    } else {
        weight_prep_kernel<<<FOUTN, 256, 0, stream>>>(weight, mw, mw2);
        dcoef_kernel<<<NB, FOUTN, 0, stream>>>(mw2, sty, dco);
        conv_kernel<<<dim3(64, FOUTN / OT, NB), 256, 0, stream>>>(x, sty, mw, dco, y);
    }
}